// Round 5
// baseline (7322.781 us; speedup 1.0000x reference)
//
#include <hip/hip_runtime.h>
#include <stdint.h>

#define KS   21
#define HALO 10
#define TH   16
#define TW   256
#define PH   (TH + 2*HALO)   // 36 rows
#define PWH  280             // padded halves per row (276 used + 4 zeroed)
#define PWD  (PWH / 2)       // 140 dwords per row
#define HDIM 768

typedef _Float16 half2f __attribute__((ext_vector_type(2)));

__device__ __forceinline__ int reflect_idx(int x, int n) {
    if (x < 0) x = -x;
    if (x >= n) x = 2 * n - 2 - x;
    return x;
}

__device__ __forceinline__ uint32_t pack2(float a, float b) {
    return __builtin_bit_cast(uint32_t, __builtin_amdgcn_cvt_pkrtz(a, b));
}

__device__ __forceinline__ float fdot2f(half2f a, half2f b, float c) {
    return __builtin_amdgcn_fdot2(a, b, c, false);   // v_dot2_f32_f16
}

__device__ __forceinline__ half2f h2_from_u32(uint32_t u) {
    return __builtin_bit_cast(half2f, u);
}

__global__ __launch_bounds__(256, 4)
void blur_by_kernel(const float* __restrict__ in,
                    const float* __restrict__ kern,
                    float* __restrict__ out) {
    __shared__ uint32_t tile[PH * PWD];   // f16 pairs, 20160 B

    const int bx  = blockIdx.x;   // 0..2
    const int by  = blockIdx.y;   // 0..47
    const int bc  = blockIdx.z;   // b*3+c
    const int b   = bc / 3;
    const int tid = threadIdx.x;
    const int lane = tid & 63;
    const int w    = tid >> 6;    // wave -> output rows 4w..4w+3

    const float* plane = in + (size_t)bc * (HDIM * HDIM);
    const int y0 = by * TH - HALO;
    const int x0 = bx * TW - HALO;

    // ---- stage 36 x 280 halves (f16, RTZ) with reflect padding; cols >=276 zero ----
    for (int idx = tid; idx < PH * PWD; idx += 256) {
        int r  = idx / PWD;
        int cd = idx - r * PWD;
        int c0 = 2 * cd;
        int gy = reflect_idx(y0 + r, HDIM);
        const float* grow = plane + gy * HDIM;
        float f0 = (c0     < TW + 2*HALO) ? grow[reflect_idx(x0 + c0,     HDIM)] : 0.f;
        float f1 = (c0 + 1 < TW + 2*HALO) ? grow[reflect_idx(x0 + c0 + 1, HDIM)] : 0.f;
        tile[idx] = pack2(f0, f1);
    }
    __syncthreads();

    const float* kb = kern + b * (KS * KS);   // block-uniform -> scalar loads

    float acc[4][4] = {};
    uint32_t krows[4][11];                    // rolling packed kernel rows
    const int dwbase = lane * 2;              // lane's dword col base (halves col = 4*lane)

    #pragma unroll
    for (int t = 0; t < 24; ++t) {
        // pack new kernel row t (used by r=0 now, r=1..3 in next 3 iters)
        if (t <= 20) {
            #pragma unroll
            for (int j = 0; j < 10; ++j)
                krows[t & 3][j] = pack2(kb[t * KS + 2*j], kb[t * KS + 2*j + 1]);
            krows[t & 3][10] = pack2(kb[t * KS + 20], 0.f);
        }

        // load 13 dwords (26 halves) of input row, wave-uniform row + 8B/lane
        uint32_t xd[13];
        const uint32_t* lrow = &tile[(w * 4 + t) * PWD + dwbase];
        #pragma unroll
        for (int j = 0; j < 6; ++j) {
            uint2 v = *(const uint2*)(lrow + 2*j);   // ds_read_b64, 8B-aligned
            xd[2*j] = v.x; xd[2*j + 1] = v.y;
        }
        xd[12] = lrow[12];

        // odd-parity pairs: od[j] = (x[2j+1], x[2j+2])
        uint32_t od[12];
        #pragma unroll
        for (int j = 0; j < 12; ++j)
            od[j] = __builtin_amdgcn_alignbit(xd[j + 1], xd[j], 16);

        #pragma unroll
        for (int r = 0; r < 4; ++r) {
            const int ki = t - r;
            if (ki >= 0 && ki <= 20) {
                const uint32_t* kr = krows[ki & 3];
                #pragma unroll
                for (int j = 0; j < 11; ++j) {
                    half2f kv = h2_from_u32(kr[j]);
                    acc[r][0] = fdot2f(kv, h2_from_u32(xd[j]),     acc[r][0]);
                    acc[r][1] = fdot2f(kv, h2_from_u32(od[j]),     acc[r][1]);
                    acc[r][2] = fdot2f(kv, h2_from_u32(xd[j + 1]), acc[r][2]);
                    acc[r][3] = fdot2f(kv, h2_from_u32(od[j + 1]), acc[r][3]);
                }
            }
        }
    }

    float* oplane = out + (size_t)bc * (HDIM * HDIM);
    const int gx = bx * TW + lane * 4;
    const int gy = by * TH + w * 4;
    #pragma unroll
    for (int r = 0; r < 4; ++r) {
        float4 v = make_float4(acc[r][0], acc[r][1], acc[r][2], acc[r][3]);
        *(float4*)&oplane[(size_t)(gy + r) * HDIM + gx] = v;
    }
}

extern "C" void kernel_launch(void* const* d_in, const int* in_sizes, int n_in,
                              void* d_out, int out_size, void* d_ws, size_t ws_size,
                              hipStream_t stream) {
    const float* in   = (const float*)d_in[0];   // (16,3,768,768) fp32
    const float* kern = (const float*)d_in[1];   // (16,21,21) fp32
    float* out = (float*)d_out;

    dim3 grid(HDIM / TW, HDIM / TH, 16 * 3);     // 3 x 48 x 48
    dim3 block(256);
    blur_by_kernel<<<grid, block, 0, stream>>>(in, kern, out);
}